// Round 1
// baseline (4275.718 us; speedup 1.0000x reference)
//
#include <hip/hip_runtime.h>
#include <math.h>

// ConvGRU, fused per-timestep kernel.
// x: (B=4, C_in=16, T=64, H=64, W=64) fp32
// Wx: (96, 16, 3, 3), bx: (96,), Wh: (96, 32, 3, 3)
// Only gate rows [0,32) (z) and [64,96) (n) are ever used (r is dead in the ref).
// h ping-pongs between d_ws (2 MB) and d_out (2 MB); step 63 writes d_out.

#define HW 4096  // 64*64

__global__ __launch_bounds__(256) void convgru_step(
    const float* __restrict__ x, const float* __restrict__ Wx,
    const float* __restrict__ bx, const float* __restrict__ Wh,
    const float* __restrict__ hsrc, float* __restrict__ hdst, int t)
{
    const int p  = blockIdx.x * 256 + threadIdx.x;  // pixel 0..4095
    const int c  = blockIdx.y;                      // output channel 0..31 (uniform!)
    const int b  = blockIdx.z;                      // batch 0..3
    const int y  = p >> 6;
    const int x0 = p & 63;

    float az = bx[c];        // z-gate pre-activation
    float an = bx[c + 64];   // n-gate pre-activation

    // ---- input projection: conv(x_t, Wx) for rows c and c+64 ----
    for (int cin = 0; cin < 16; ++cin) {
        const float* xp  = x + (size_t)((b * 16 + cin) * 64 + t) * HW;
        const float* wzp = Wx + (size_t)(c * 16 + cin) * 9;
        const float* wnp = Wx + (size_t)((c + 64) * 16 + cin) * 9;
        float wz[9], wn[9];
        #pragma unroll
        for (int k = 0; k < 9; ++k) { wz[k] = wzp[k]; wn[k] = wnp[k]; }
        #pragma unroll
        for (int ky = 0; ky < 3; ++ky) {
            const int yy = y + ky - 1;
            if ((unsigned)yy < 64u) {
                const float* row = xp + (yy << 6);
                #pragma unroll
                for (int kx = 0; kx < 3; ++kx) {
                    const int xx = x0 + kx - 1;
                    if ((unsigned)xx < 64u) {
                        const float v = row[xx];
                        az = fmaf(v, wz[ky * 3 + kx], az);
                        an = fmaf(v, wn[ky * 3 + kx], an);
                    }
                }
            }
        }
    }

    // ---- recurrent projection: conv(h, Wh) for rows c and c+64 ----
    for (int hc = 0; hc < 32; ++hc) {
        const float* hp  = hsrc + (size_t)(b * 32 + hc) * HW;
        const float* wzp = Wh + (size_t)(c * 32 + hc) * 9;
        const float* wnp = Wh + (size_t)((c + 64) * 32 + hc) * 9;
        float wz[9], wn[9];
        #pragma unroll
        for (int k = 0; k < 9; ++k) { wz[k] = wzp[k]; wn[k] = wnp[k]; }
        #pragma unroll
        for (int ky = 0; ky < 3; ++ky) {
            const int yy = y + ky - 1;
            if ((unsigned)yy < 64u) {
                const float* row = hp + (yy << 6);
                #pragma unroll
                for (int kx = 0; kx < 3; ++kx) {
                    const int xx = x0 + kx - 1;
                    if ((unsigned)xx < 64u) {
                        const float v = row[xx];
                        az = fmaf(v, wz[ky * 3 + kx], az);
                        an = fmaf(v, wn[ky * 3 + kx], an);
                    }
                }
            }
        }
    }

    const float hprev = hsrc[(size_t)(b * 32 + c) * HW + p];
    const float z = 1.0f / (1.0f + expf(-az));
    const float n = tanhf(an);
    hdst[(size_t)(b * 32 + c) * HW + p] = (1.0f - z) * hprev + z * n;
}

extern "C" void kernel_launch(void* const* d_in, const int* in_sizes, int n_in,
                              void* d_out, int out_size, void* d_ws, size_t ws_size,
                              hipStream_t stream) {
    const float* x  = (const float*)d_in[0];
    const float* Wx = (const float*)d_in[1];
    const float* bx = (const float*)d_in[2];
    const float* Wh = (const float*)d_in[3];
    float* out = (float*)d_out;
    float* ws  = (float*)d_ws;

    // h0 = zeros lives in d_out for step 0 (parity: even steps read out/write ws,
    // odd steps read ws/write out; t=63 is odd -> final h lands in d_out).
    hipMemsetAsync(d_out, 0, (size_t)524288 * sizeof(float), stream);

    dim3 grid(16, 32, 4), block(256);
    for (int t = 0; t < 64; ++t) {
        const float* src = (t & 1) ? ws : out;
        float*       dst = (t & 1) ? out : ws;
        hipLaunchKernelGGL(convgru_step, grid, block, 0, stream,
                           x, Wx, bx, Wh, src, dst, t);
    }
}

// Round 2
// 1864.592 us; speedup vs baseline: 2.2931x; 2.2931x over previous
//
#include <hip/hip_runtime.h>
#include <math.h>

// ConvGRU fused per-timestep kernel, LDS-tiled.
// x: (4,16,64,64,64) f32, Wx: (96,16,3,3), bx: (96), Wh: (96,32,3,3).
// r-gate is dead in the reference: only gate rows [0,32) (z) and [64,96) (n).
// Block = 4x64 pixel tile x 4 output channels; inputs staged in LDS in 3
// chunks of 16 channels. h ping-pongs d_out <-> d_ws; t=63 writes d_out.

#define LW 66                      // padded LDS row width (64 + 2 halo cols)
#define LDS_FLOATS (16 * 6 * LW)   // 16 ch x 6 rows x 66 = 25344 B

__global__ __launch_bounds__(256, 2) void convgru_step(
    const float* __restrict__ x, const float* __restrict__ Wx,
    const float* __restrict__ bx, const float* __restrict__ Wh,
    const float* __restrict__ hsrc, float* __restrict__ hdst, int t)
{
    __shared__ float lds[LDS_FLOATS];
    const int tx    = threadIdx.x;
    const int y0    = blockIdx.x * 4;        // tile rows y0..y0+3
    const int cbase = blockIdx.y * 4;        // output channels cbase..cbase+3 (uniform)
    const int b     = blockIdx.z;
    const int row   = tx >> 6;               // 0..3 within tile
    const int col   = tx & 63;

    // zero the halo columns once (staging never writes cols 0 / 65)
    if (tx < 192) {
        int rowg = tx >> 1;                  // 0..95 = ch*6 + r
        lds[rowg * LW + ((tx & 1) ? 65 : 0)] = 0.0f;
    }

    float acc[8];                            // [ch i][gate z=0,n=1]
    #pragma unroll
    for (int i = 0; i < 4; ++i) {
        acc[2 * i]     = bx[cbase + i];
        acc[2 * i + 1] = bx[64 + cbase + i];
    }

    for (int chunk = 0; chunk < 3; ++chunk) {
        const float* src;
        const float* wbase;
        size_t chanStride;
        int wstride;
        if (chunk == 0) {
            // x channel ch: x[((b*16+ch)*64 + t)*4096]
            src = x + ((size_t)(b * 16) * 64 + t) * 4096;
            chanStride = (size_t)64 * 4096;
            wbase = Wx; wstride = 16;
        } else {
            src = hsrc + (size_t)(b * 32 + (chunk - 1) * 16) * 4096;
            chanStride = 4096;
            wbase = Wh + (size_t)(chunk - 1) * 16 * 9;  // shifts cin by 16 for chunk 2
            wstride = 32;
        }

        __syncthreads();  // previous compute (or halo zeroing) done before restage
        // stage 16 channels x 6 halo rows x 64 cols as float4 (1536 tasks)
        #pragma unroll
        for (int i = 0; i < 6; ++i) {
            int task = i * 256 + tx;
            int f4   = task & 15;
            int rowg = task >> 4;            // 0..95
            int ch   = rowg / 6;
            int r    = rowg - ch * 6;
            int yy   = y0 - 1 + r;
            float4 v = make_float4(0.f, 0.f, 0.f, 0.f);
            if ((unsigned)yy < 64u)
                v = *(const float4*)(src + ch * chanStride + yy * 64 + f4 * 4);
            float* dst = &lds[rowg * LW + 1 + f4 * 4];
            dst[0] = v.x; dst[1] = v.y; dst[2] = v.z; dst[3] = v.w;
        }
        __syncthreads();

        for (int cin = 0; cin < 16; ++cin) {
            const float* lb = &lds[cin * 6 * LW + row * LW + col];
            float v[9];
            v[0] = lb[0];        v[1] = lb[1];        v[2] = lb[2];
            v[3] = lb[LW];       v[4] = lb[LW + 1];   v[5] = lb[LW + 2];
            v[6] = lb[2 * LW];   v[7] = lb[2 * LW + 1]; v[8] = lb[2 * LW + 2];
            #pragma unroll
            for (int i = 0; i < 4; ++i) {
                const float* wz = wbase + ((size_t)(cbase + i) * wstride + cin) * 9;
                const float* wn = wbase + ((size_t)(64 + cbase + i) * wstride + cin) * 9;
                #pragma unroll
                for (int k = 0; k < 9; ++k) {
                    acc[2 * i]     = fmaf(v[k], wz[k], acc[2 * i]);
                    acc[2 * i + 1] = fmaf(v[k], wn[k], acc[2 * i + 1]);
                }
            }
        }
    }

    const int p = (y0 + row) * 64 + col;
    #pragma unroll
    for (int i = 0; i < 4; ++i) {
        float hprev = hsrc[(size_t)(b * 32 + cbase + i) * 4096 + p];
        float z = 1.0f / (1.0f + __expf(-acc[2 * i]));
        float e = __expf(2.0f * acc[2 * i + 1]);
        float n = 1.0f - 2.0f / (e + 1.0f);          // tanh, overflow-safe
        hdst[(size_t)(b * 32 + cbase + i) * 4096 + p] = (1.0f - z) * hprev + z * n;
    }
}

extern "C" void kernel_launch(void* const* d_in, const int* in_sizes, int n_in,
                              void* d_out, int out_size, void* d_ws, size_t ws_size,
                              hipStream_t stream) {
    const float* x  = (const float*)d_in[0];
    const float* Wx = (const float*)d_in[1];
    const float* bx = (const float*)d_in[2];
    const float* Wh = (const float*)d_in[3];
    float* out = (float*)d_out;
    float* ws  = (float*)d_ws;

    // h0 = zeros in d_out (even t: read out -> write ws; odd t: read ws -> write out;
    // t=63 odd => final h lands in d_out).
    hipMemsetAsync(d_out, 0, (size_t)524288 * sizeof(float), stream);

    dim3 grid(16, 8, 4), block(256);
    for (int t = 0; t < 64; ++t) {
        const float* src = (t & 1) ? ws : out;
        float*       dst = (t & 1) ? out : ws;
        hipLaunchKernelGGL(convgru_step, grid, block, 0, stream,
                           x, Wx, bx, Wh, src, dst, t);
    }
}